// Round 1
// baseline (306.451 us; speedup 1.0000x reference)
//
#include <hip/hip_runtime.h>
#include <hip/hip_bf16.h>
#include <math.h>

#define B_  8
#define L_  4096
#define T_  128
#define DH  1024
#define DG  256
#define DP  256
#define BK  64
#define ZCH 8          // z split-K chunks

typedef short bf16x8 __attribute__((ext_vector_type(8)));
typedef float f32x4  __attribute__((ext_vector_type(4)));
typedef unsigned short u16x8 __attribute__((ext_vector_type(8)));

#define AS1(p) ((const __attribute__((address_space(1))) void*)(p))
#define AS3(p) ((__attribute__((address_space(3))) void*)(p))

__device__ __forceinline__ unsigned short f2bf(float f) {
    unsigned u = __float_as_uint(f);
    unsigned r = (u + 0x7FFFu + ((u >> 16) & 1u)) >> 16;  // RNE
    return (unsigned short)r;
}

// ---------------- Kernel W: Wct[d,g] = (1/16) * sum_p Wk[d,p] * Wq[g,p]   (bf16 out)
__global__ __launch_bounds__(256) void wct_kernel(const float* __restrict__ Wk,
                                                  const float* __restrict__ Wq,
                                                  unsigned short* __restrict__ Wct) {
    __shared__ __attribute__((aligned(16))) unsigned short As[128 * BK];
    __shared__ __attribute__((aligned(16))) unsigned short Bs[64 * BK];
    const int n0 = blockIdx.x * 64, m0 = blockIdx.y * 128;
    const int tid = threadIdx.x, wave = tid >> 6, lane = tid & 63;
    const int lm = lane & 15, quad = lane >> 4;
    const int wm = wave >> 1, wn = wave & 1;
    const int bc = (tid & 15) * 4, br = tid >> 4;
    f32x4 acc[4][2] = {};

    for (int k0 = 0; k0 < DP; k0 += BK) {
        #pragma unroll
        for (int s = 0; s < 8; ++s) {
            const int row = br + s * 16;
            const float4 v = *(const float4*)(Wk + (size_t)(m0 + row) * DP + k0 + bc);
            ushort4 p; p.x = f2bf(v.x); p.y = f2bf(v.y); p.z = f2bf(v.z); p.w = f2bf(v.w);
            *(ushort4*)(&As[row * BK + bc]) = p;
        }
        #pragma unroll
        for (int s = 0; s < 4; ++s) {
            const int row = br + s * 16;
            const float4 v = *(const float4*)(Wq + (size_t)(n0 + row) * DP + k0 + bc);
            ushort4 p; p.x = f2bf(v.x); p.y = f2bf(v.y); p.z = f2bf(v.z); p.w = f2bf(v.w);
            *(ushort4*)(&Bs[row * BK + bc]) = p;
        }
        __syncthreads();
        #pragma unroll
        for (int ks = 0; ks < 2; ++ks) {
            bf16x8 a[4], bf[2];
            #pragma unroll
            for (int i = 0; i < 4; ++i)
                a[i] = *(const bf16x8*)(&As[(wm * 64 + i * 16 + lm) * BK + ks * 32 + quad * 8]);
            #pragma unroll
            for (int j = 0; j < 2; ++j)
                bf[j] = *(const bf16x8*)(&Bs[(wn * 32 + j * 16 + lm) * BK + ks * 32 + quad * 8]);
            #pragma unroll
            for (int i = 0; i < 4; ++i)
                #pragma unroll
                for (int j = 0; j < 2; ++j)
                    acc[i][j] = __builtin_amdgcn_mfma_f32_16x16x32_bf16(a[i], bf[j], acc[i][j], 0, 0, 0);
        }
        __syncthreads();
    }
    unsigned short* Cb = Wct + (size_t)m0 * DG + n0;
    #pragma unroll
    for (int i = 0; i < 4; ++i)
        #pragma unroll
        for (int j = 0; j < 2; ++j)
            #pragma unroll
            for (int r = 0; r < 4; ++r)
                Cb[(size_t)(wm * 64 + i * 16 + quad * 4 + r) * DG + wn * 32 + j * 16 + lm] =
                    f2bf(acc[i][j][r] * 0.0625f);
}

// ---------------- Kernel Q: Qk[bt,d] = sum_g G[bt,g] * Wct[d,g]   (bf16 out)
__global__ __launch_bounds__(256) void qproj_kernel(const float* __restrict__ G,
                                                    const unsigned short* __restrict__ Wct,
                                                    unsigned short* __restrict__ Qk) {
    __shared__ __attribute__((aligned(16))) unsigned short As[128 * BK];
    __shared__ __attribute__((aligned(16))) unsigned short Bs[64 * BK];
    const int n0 = blockIdx.x * 64, m0 = blockIdx.y * 128;
    const int tid = threadIdx.x, wave = tid >> 6, lane = tid & 63;
    const int lm = lane & 15, quad = lane >> 4;
    const int wm = wave >> 1, wn = wave & 1;
    const int bc = (tid & 15) * 4, br = tid >> 4;
    const int ar = lane >> 3, akb = (lane & 7) * 8;
    f32x4 acc[4][2] = {};

    for (int k0 = 0; k0 < DG; k0 += BK) {
        #pragma unroll
        for (int s = 0; s < 8; ++s) {
            const int row = br + s * 16;
            const float4 v = *(const float4*)(G + (size_t)(m0 + row) * DG + k0 + bc);
            ushort4 p; p.x = f2bf(v.x); p.y = f2bf(v.y); p.z = f2bf(v.z); p.w = f2bf(v.w);
            *(ushort4*)(&As[row * BK + bc]) = p;
        }
        #pragma unroll
        for (int s = 0; s < 2; ++s) {
            const int rowb = s * 32 + wave * 8;
            const unsigned short* gp = Wct + (size_t)(n0 + rowb + ar) * DG + k0 + akb;
            __builtin_amdgcn_global_load_lds(AS1(gp), AS3(&Bs[rowb * BK]), 16, 0, 0);
        }
        __syncthreads();
        #pragma unroll
        for (int ks = 0; ks < 2; ++ks) {
            bf16x8 a[4], bf[2];
            #pragma unroll
            for (int i = 0; i < 4; ++i)
                a[i] = *(const bf16x8*)(&As[(wm * 64 + i * 16 + lm) * BK + ks * 32 + quad * 8]);
            #pragma unroll
            for (int j = 0; j < 2; ++j)
                bf[j] = *(const bf16x8*)(&Bs[(wn * 32 + j * 16 + lm) * BK + ks * 32 + quad * 8]);
            #pragma unroll
            for (int i = 0; i < 4; ++i)
                #pragma unroll
                for (int j = 0; j < 2; ++j)
                    acc[i][j] = __builtin_amdgcn_mfma_f32_16x16x32_bf16(a[i], bf[j], acc[i][j], 0, 0, 0);
        }
        __syncthreads();
    }
    unsigned short* Cb = Qk + (size_t)m0 * DH + n0;
    #pragma unroll
    for (int i = 0; i < 4; ++i)
        #pragma unroll
        for (int j = 0; j < 2; ++j)
            #pragma unroll
            for (int r = 0; r < 4; ++r)
                Cb[(size_t)(wm * 64 + i * 16 + quad * 4 + r) * DH + wn * 32 + j * 16 + lm] =
                    f2bf(acc[i][j][r]);
}

// ---------------- Kernel S: fused logits+exp.  alpha_un[b,t,l] = mask? 0 : exp(Qk[b,t,:].H[b,l,:])
// Also: writes bf16 copy of H (H16) for the z pass (conversion already done for LDS staging),
// and atomically accumulates rowsum[b*T+t].
// tile 128t x 64l, full K=1024; grid (L/64, B) = 512 blocks, XCD-swizzled so each b owns one XCD
// (Qk[b] fetched into exactly one L2).
__global__ __launch_bounds__(256, 2) void fusedsm_kernel(const unsigned short* __restrict__ Qk,
                                                         const float* __restrict__ H,
                                                         const int* __restrict__ mask,
                                                         unsigned short* __restrict__ alpha,
                                                         float* __restrict__ rowsum,
                                                         unsigned short* __restrict__ H16) {
    __shared__ __attribute__((aligned(16))) unsigned short As[T_ * BK];   // [t][k]
    __shared__ __attribute__((aligned(16))) unsigned short Bs[64 * BK];   // [l][k]
    __shared__ float rs[T_];
    // XCD swizzle: physical linear id -> (b = lin % 8, l0 = lin / 8). 512 blocks, 8 XCDs:
    // all 64 blocks of batch b land on XCD b.
    const int blin = blockIdx.x + (L_ / 64) * blockIdx.y;
    const int b = blin & 7, l0 = (blin >> 3) * 64;
    const int tid = threadIdx.x, wave = tid >> 6, lane = tid & 63;
    const unsigned short* Ab = Qk + (size_t)b * T_ * DH;
    const float*          Hb = H + ((size_t)b * L_ + l0) * DH;
    unsigned short*     H16b = H16 + ((size_t)b * L_ + l0) * DH;

    const int lm = lane & 15, quad = lane >> 4;
    const int wm = wave >> 1, wn = wave & 1;
    f32x4 acc[4][2] = {};
    const int ar = lane >> 3, akb = (lane & 7) * 8;
    const int bc = (tid & 15) * 4, br = tid >> 4;

    if (tid < T_) rs[tid] = 0.f;

    for (int k0 = 0; k0 < DH; k0 += BK) {
        #pragma unroll
        for (int s = 0; s < 4; ++s) {   // A: Qk 128 t-rows x 64 k, async
            const int rowb = s * 32 + wave * 8;
            const unsigned short* gp = Ab + (size_t)(rowb + ar) * DH + k0 + akb;
            __builtin_amdgcn_global_load_lds(AS1(gp), AS3(&As[rowb * BK]), 16, 0, 0);
        }
        #pragma unroll
        for (int s = 0; s < 4; ++s) {   // B: H 64 l-rows x 64 k fp32 -> bf16 (LDS + spill to H16)
            const int row = br + s * 16;
            const float4 v = *(const float4*)(Hb + (size_t)row * DH + k0 + bc);
            ushort4 pk; pk.x = f2bf(v.x); pk.y = f2bf(v.y); pk.z = f2bf(v.z); pk.w = f2bf(v.w);
            *(ushort4*)(&Bs[row * BK + bc]) = pk;
            *(ushort4*)(H16b + (size_t)row * DH + k0 + bc) = pk;   // bf16 H for z pass
        }
        __syncthreads();
        #pragma unroll
        for (int ks = 0; ks < 2; ++ks) {
            bf16x8 a[4], bf[2];
            #pragma unroll
            for (int i = 0; i < 4; ++i)
                a[i] = *(const bf16x8*)(&As[(wm * 64 + i * 16 + lm) * BK + ks * 32 + quad * 8]);
            #pragma unroll
            for (int j = 0; j < 2; ++j)
                bf[j] = *(const bf16x8*)(&Bs[(wn * 32 + j * 16 + lm) * BK + ks * 32 + quad * 8]);
            #pragma unroll
            for (int i = 0; i < 4; ++i)
                #pragma unroll
                for (int j = 0; j < 2; ++j)
                    acc[i][j] = __builtin_amdgcn_mfma_f32_16x16x32_bf16(a[i], bf[j], acc[i][j], 0, 0, 0);
        }
        __syncthreads();
    }

    // epilogue: mask, exp, store bf16 alpha, accumulate row sums
    const int c0 = l0 + wn * 32 + lm;          // column for j=0 (j=1 adds 16)
    const int mk0 = mask[(size_t)b * L_ + c0];
    const int mk1 = mask[(size_t)b * L_ + c0 + 16];
    unsigned short* Arow = alpha + (size_t)b * T_ * L_ + l0 + wn * 32 + lm;
    #pragma unroll
    for (int i = 0; i < 4; ++i) {
        #pragma unroll
        for (int r = 0; r < 4; ++r) {
            const int row = wm * 64 + i * 16 + quad * 4 + r;
            float e0 = mk0 ? 0.f : __expf(acc[i][0][r]);
            float e1 = mk1 ? 0.f : __expf(acc[i][1][r]);
            Arow[(size_t)row * L_]      = f2bf(e0);
            Arow[(size_t)row * L_ + 16] = f2bf(e1);
            float part = e0 + e1;                    // sum over this lane's 2 cols
            part += __shfl_xor(part, 1, 64);
            part += __shfl_xor(part, 2, 64);
            part += __shfl_xor(part, 4, 64);
            part += __shfl_xor(part, 8, 64);         // now = sum over 32 cols (this wn half)
            if (lm == 0) atomicAdd(&rs[row], part);
        }
    }
    __syncthreads();
    if (tid < T_) atomicAdd(&rowsum[(size_t)b * T_ + tid], rs[tid]);
}

// ---------------- Kernel 4: Z += (alpha_un(bf16) . H16(bf16, swizzled LDS transpose)) / rowsum
// tile 128t x 128d, L-split 8; grid 512 blocks, XCD-swizzled so the 8 d0-blocks sharing an
// alpha chunk land on one XCD (chunk ch owns XCD ch). Scaled partials atomicAdd'ed into Z
// (no zpart buffer, no reduce kernel).
__global__ __launch_bounds__(256, 2) void z_kernel(const unsigned short* __restrict__ alpha,
                                                   const unsigned short* __restrict__ H16,
                                                   const float* __restrict__ rowsum,
                                                   float* __restrict__ Z) {
    __shared__ __attribute__((aligned(16))) unsigned short As[T_ * BK];   // [t][l]
    __shared__ __attribute__((aligned(16))) unsigned B32[128 * 32];       // swizzled [d][lp]
    // XCD swizzle: lin % 8 -> ch (so all blocks of chunk ch share one XCD's L2 for alpha),
    // remaining bits -> (b, d0). Bijective over the 512-block grid.
    const int blin = blockIdx.x + 8 * (blockIdx.y + 8 * blockIdx.z);
    const int ch = blin & 7, rest = blin >> 3;
    const int b = rest & 7, d0 = (rest >> 3) * 128;
    const int tid = threadIdx.x, wave = tid >> 6, lane = tid & 63;
    const int Lc = L_ / ZCH;                       // 512
    const unsigned short* Ab = alpha + (size_t)b * T_ * L_ + ch * Lc;
    const unsigned short* Hb = H16 + ((size_t)b * L_ + ch * Lc) * DH + d0;

    const int lm = lane & 15, quad = lane >> 4;
    const int wm = wave >> 1, wn = wave & 1;
    f32x4 acc[4][4] = {};
    const int ar = lane >> 3, akb = (lane & 7) * 8;
    const int dg = tid & 15, lph = tid >> 4;       // dg: d-octet, lph: 4-l-row group

    for (int k0 = 0; k0 < Lc; k0 += BK) {
        #pragma unroll
        for (int s = 0; s < 4; ++s) {   // A: alpha 128 rows x 64 l, async
            const int rowb = s * 32 + wave * 8;
            const unsigned short* gp = Ab + (size_t)(rowb + ar) * L_ + k0 + akb;
            __builtin_amdgcn_global_load_lds(AS1(gp), AS3(&As[rowb * BK]), 16, 0, 0);
        }
        // B: H16 64 l-rows x 128 d bf16 -> transposed, l-pairs packed in uint, block-rot swizzle
        {
            const unsigned short* r = Hb + (size_t)(k0 + 4 * lph) * DH + dg * 8;
            u16x8 u[4];
            #pragma unroll
            for (int rr = 0; rr < 4; ++rr)
                u[rr] = *(const u16x8*)(r + (size_t)rr * DH);
            const int lp0 = 2 * lph;
            #pragma unroll
            for (int i = 0; i < 8; ++i) {
                const int d   = dg * 8 + i;
                const int rot = ((i + (dg & 7)) << 2) & 31;
                B32[d * 32 + ((lp0 + rot) & 31)] =
                    (unsigned)u[0][i] | ((unsigned)u[1][i] << 16);
                B32[d * 32 + ((lp0 + 1 + rot) & 31)] =
                    (unsigned)u[2][i] | ((unsigned)u[3][i] << 16);
            }
        }
        __syncthreads();
        #pragma unroll
        for (int ks = 0; ks < 2; ++ks) {
            bf16x8 a[4], bf[4];
            #pragma unroll
            for (int i = 0; i < 4; ++i)
                a[i] = *(const bf16x8*)(&As[(wm * 64 + i * 16 + lm) * BK + ks * 32 + quad * 8]);
            #pragma unroll
            for (int j = 0; j < 4; ++j) {
                const int d   = wn * 64 + j * 16 + lm;
                const int rot = (((d & 7) + ((d >> 3) & 7)) << 2) & 31;
                bf[j] = *(const bf16x8*)(&B32[d * 32 + ((ks * 16 + quad * 4 + rot) & 31)]);
            }
            #pragma unroll
            for (int i = 0; i < 4; ++i)
                #pragma unroll
                for (int j = 0; j < 4; ++j)
                    acc[i][j] = __builtin_amdgcn_mfma_f32_16x16x32_bf16(a[i], bf[j], acc[i][j], 0, 0, 0);
        }
        __syncthreads();
    }
    // epilogue: scale by 1/rowsum and accumulate into Z directly
    float* Zb = Z + ((size_t)b * T_) * DH + d0;
    const float* rsb = rowsum + (size_t)b * T_;
    #pragma unroll
    for (int i = 0; i < 4; ++i) {
        #pragma unroll
        for (int r = 0; r < 4; ++r) {
            const int row = wm * 64 + i * 16 + quad * 4 + r;
            const float inv = 1.0f / rsb[row];
            #pragma unroll
            for (int j = 0; j < 4; ++j)
                atomicAdd(&Zb[(size_t)row * DH + wn * 64 + j * 16 + lm], acc[i][j][r] * inv);
        }
    }
}

extern "C" void kernel_launch(void* const* d_in, const int* in_sizes, int n_in,
                              void* d_out, int out_size, void* d_ws, size_t ws_size,
                              hipStream_t stream) {
    const float* H    = (const float*)d_in[0];
    const float* G    = (const float*)d_in[1];
    const int*   mask = (const int*)d_in[2];
    const float* Wk   = (const float*)d_in[3];
    const float* Wq   = (const float*)d_in[4];
    float* Z = (float*)d_out;

    char* ws = (char*)d_ws;
    unsigned short* Wct    = (unsigned short*)ws;                        // 512 KB
    unsigned short* Qk     = (unsigned short*)(ws + ((size_t)1 << 20));  //   2 MB
    unsigned short* alpha  = (unsigned short*)(ws + ((size_t)4 << 20));  //   8 MB
    float*          rowsum = (float*)(ws + ((size_t)13 << 20));          //   4 KB
    unsigned short* H16    = (unsigned short*)(ws + ((size_t)14 << 20)); //  64 MB

    hipMemsetAsync(rowsum, 0, (size_t)B_ * T_ * sizeof(float), stream);
    hipMemsetAsync(Z, 0, (size_t)B_ * T_ * DH * sizeof(float), stream);
    wct_kernel<<<dim3(DG / 64, DH / 128), 256, 0, stream>>>(Wk, Wq, Wct);
    qproj_kernel<<<dim3(DH / 64, (B_ * T_) / 128), 256, 0, stream>>>(G, Wct, Qk);
    fusedsm_kernel<<<dim3(L_ / 64, B_), 256, 0, stream>>>(Qk, H, mask, alpha, rowsum, H16);
    z_kernel<<<dim3(DH / 128, B_, ZCH), 256, 0, stream>>>(alpha, H16, rowsum, Z);
}

// Round 2
// 286.275 us; speedup vs baseline: 1.0705x; 1.0705x over previous
//
#include <hip/hip_runtime.h>
#include <hip/hip_bf16.h>
#include <math.h>

#define B_  8
#define L_  4096
#define T_  128
#define DH  1024
#define DG  256
#define DP  256
#define BK  64
#define ZCH 8          // z split-K chunks

typedef short bf16x8 __attribute__((ext_vector_type(8)));
typedef float f32x4  __attribute__((ext_vector_type(4)));
typedef unsigned short u16x8 __attribute__((ext_vector_type(8)));

#define AS1(p) ((const __attribute__((address_space(1))) void*)(p))
#define AS3(p) ((__attribute__((address_space(3))) void*)(p))

__device__ __forceinline__ unsigned short f2bf(float f) {
    unsigned u = __float_as_uint(f);
    unsigned r = (u + 0x7FFFu + ((u >> 16) & 1u)) >> 16;  // RNE
    return (unsigned short)r;
}

// ---------------- Kernel W: Wct[d,g] = (1/16) * sum_p Wk[d,p] * Wq[g,p]   (bf16 out)
__global__ __launch_bounds__(256) void wct_kernel(const float* __restrict__ Wk,
                                                  const float* __restrict__ Wq,
                                                  unsigned short* __restrict__ Wct) {
    __shared__ __attribute__((aligned(16))) unsigned short As[128 * BK];
    __shared__ __attribute__((aligned(16))) unsigned short Bs[64 * BK];
    const int n0 = blockIdx.x * 64, m0 = blockIdx.y * 128;
    const int tid = threadIdx.x, wave = tid >> 6, lane = tid & 63;
    const int lm = lane & 15, quad = lane >> 4;
    const int wm = wave >> 1, wn = wave & 1;
    const int bc = (tid & 15) * 4, br = tid >> 4;
    f32x4 acc[4][2] = {};

    for (int k0 = 0; k0 < DP; k0 += BK) {
        #pragma unroll
        for (int s = 0; s < 8; ++s) {
            const int row = br + s * 16;
            const float4 v = *(const float4*)(Wk + (size_t)(m0 + row) * DP + k0 + bc);
            ushort4 p; p.x = f2bf(v.x); p.y = f2bf(v.y); p.z = f2bf(v.z); p.w = f2bf(v.w);
            *(ushort4*)(&As[row * BK + bc]) = p;
        }
        #pragma unroll
        for (int s = 0; s < 4; ++s) {
            const int row = br + s * 16;
            const float4 v = *(const float4*)(Wq + (size_t)(n0 + row) * DP + k0 + bc);
            ushort4 p; p.x = f2bf(v.x); p.y = f2bf(v.y); p.z = f2bf(v.z); p.w = f2bf(v.w);
            *(ushort4*)(&Bs[row * BK + bc]) = p;
        }
        __syncthreads();
        #pragma unroll
        for (int ks = 0; ks < 2; ++ks) {
            bf16x8 a[4], bf[2];
            #pragma unroll
            for (int i = 0; i < 4; ++i)
                a[i] = *(const bf16x8*)(&As[(wm * 64 + i * 16 + lm) * BK + ks * 32 + quad * 8]);
            #pragma unroll
            for (int j = 0; j < 2; ++j)
                bf[j] = *(const bf16x8*)(&Bs[(wn * 32 + j * 16 + lm) * BK + ks * 32 + quad * 8]);
            #pragma unroll
            for (int i = 0; i < 4; ++i)
                #pragma unroll
                for (int j = 0; j < 2; ++j)
                    acc[i][j] = __builtin_amdgcn_mfma_f32_16x16x32_bf16(a[i], bf[j], acc[i][j], 0, 0, 0);
        }
        __syncthreads();
    }
    unsigned short* Cb = Wct + (size_t)m0 * DG + n0;
    #pragma unroll
    for (int i = 0; i < 4; ++i)
        #pragma unroll
        for (int j = 0; j < 2; ++j)
            #pragma unroll
            for (int r = 0; r < 4; ++r)
                Cb[(size_t)(wm * 64 + i * 16 + quad * 4 + r) * DG + wn * 32 + j * 16 + lm] =
                    f2bf(acc[i][j][r] * 0.0625f);
}

// ---------------- Kernel Q: Qk[bt,d] = sum_g G[bt,g] * Wct[d,g]   (bf16 out)
__global__ __launch_bounds__(256) void qproj_kernel(const float* __restrict__ G,
                                                    const unsigned short* __restrict__ Wct,
                                                    unsigned short* __restrict__ Qk) {
    __shared__ __attribute__((aligned(16))) unsigned short As[128 * BK];
    __shared__ __attribute__((aligned(16))) unsigned short Bs[64 * BK];
    const int n0 = blockIdx.x * 64, m0 = blockIdx.y * 128;
    const int tid = threadIdx.x, wave = tid >> 6, lane = tid & 63;
    const int lm = lane & 15, quad = lane >> 4;
    const int wm = wave >> 1, wn = wave & 1;
    const int bc = (tid & 15) * 4, br = tid >> 4;
    const int ar = lane >> 3, akb = (lane & 7) * 8;
    f32x4 acc[4][2] = {};

    for (int k0 = 0; k0 < DG; k0 += BK) {
        #pragma unroll
        for (int s = 0; s < 8; ++s) {
            const int row = br + s * 16;
            const float4 v = *(const float4*)(G + (size_t)(m0 + row) * DG + k0 + bc);
            ushort4 p; p.x = f2bf(v.x); p.y = f2bf(v.y); p.z = f2bf(v.z); p.w = f2bf(v.w);
            *(ushort4*)(&As[row * BK + bc]) = p;
        }
        #pragma unroll
        for (int s = 0; s < 2; ++s) {
            const int rowb = s * 32 + wave * 8;
            const unsigned short* gp = Wct + (size_t)(n0 + rowb + ar) * DG + k0 + akb;
            __builtin_amdgcn_global_load_lds(AS1(gp), AS3(&Bs[rowb * BK]), 16, 0, 0);
        }
        __syncthreads();
        #pragma unroll
        for (int ks = 0; ks < 2; ++ks) {
            bf16x8 a[4], bf[2];
            #pragma unroll
            for (int i = 0; i < 4; ++i)
                a[i] = *(const bf16x8*)(&As[(wm * 64 + i * 16 + lm) * BK + ks * 32 + quad * 8]);
            #pragma unroll
            for (int j = 0; j < 2; ++j)
                bf[j] = *(const bf16x8*)(&Bs[(wn * 32 + j * 16 + lm) * BK + ks * 32 + quad * 8]);
            #pragma unroll
            for (int i = 0; i < 4; ++i)
                #pragma unroll
                for (int j = 0; j < 2; ++j)
                    acc[i][j] = __builtin_amdgcn_mfma_f32_16x16x32_bf16(a[i], bf[j], acc[i][j], 0, 0, 0);
        }
        __syncthreads();
    }
    unsigned short* Cb = Qk + (size_t)m0 * DH + n0;
    #pragma unroll
    for (int i = 0; i < 4; ++i)
        #pragma unroll
        for (int j = 0; j < 2; ++j)
            #pragma unroll
            for (int r = 0; r < 4; ++r)
                Cb[(size_t)(wm * 64 + i * 16 + quad * 4 + r) * DH + wn * 32 + j * 16 + lm] =
                    f2bf(acc[i][j][r]);
}

// ---------------- Kernel S: fused logits+exp, 2-phase double-buffered pipeline.
// alpha_un[b,t,l] = mask? 0 : exp(Qk[b,t,:].H[b,l,:]); spills bf16 H (H16); accumulates rowsum.
// tile 128t x 64l, K=1024 in 16 steps; grid 512 blocks, XCD-swizzled (batch b -> XCD b).
__global__ __launch_bounds__(256, 2) void fusedsm_kernel(const unsigned short* __restrict__ Qk,
                                                         const float* __restrict__ H,
                                                         const int* __restrict__ mask,
                                                         unsigned short* __restrict__ alpha,
                                                         float* __restrict__ rowsum,
                                                         unsigned short* __restrict__ H16) {
    __shared__ __attribute__((aligned(16))) unsigned short As[2][T_ * BK];   // [t][k]
    __shared__ __attribute__((aligned(16))) unsigned short Bs[2][64 * BK];   // [l][k]
    __shared__ float rs[T_];
    const int blin = blockIdx.x + (L_ / 64) * blockIdx.y;
    const int b = blin & 7, l0 = (blin >> 3) * 64;
    const int tid = threadIdx.x, wave = tid >> 6, lane = tid & 63;
    const unsigned short* Ab = Qk + (size_t)b * T_ * DH;
    const float*          Hb = H + ((size_t)b * L_ + l0) * DH;
    unsigned short*     H16b = H16 + ((size_t)b * L_ + l0) * DH;

    const int lm = lane & 15, quad = lane >> 4;
    const int wm = wave >> 1, wn = wave & 1;
    f32x4 acc[4][2] = {};
    const int ar = lane >> 3, akb = (lane & 7) * 8;
    const int bc = (tid & 15) * 4, br = tid >> 4;

    if (tid < T_) rs[tid] = 0.f;

    // ---- prologue: stage step 0 into buffer 0
    {
        #pragma unroll
        for (int s = 0; s < 4; ++s) {
            const int rowb = s * 32 + wave * 8;
            const unsigned short* gp = Ab + (size_t)(rowb + ar) * DH + akb;
            __builtin_amdgcn_global_load_lds(AS1(gp), AS3(&As[0][rowb * BK]), 16, 0, 0);
        }
        #pragma unroll
        for (int s = 0; s < 4; ++s) {
            const int row = br + s * 16;
            const float4 v = *(const float4*)(Hb + (size_t)row * DH + bc);
            ushort4 pk; pk.x = f2bf(v.x); pk.y = f2bf(v.y); pk.z = f2bf(v.z); pk.w = f2bf(v.w);
            *(ushort4*)(&Bs[0][row * BK + bc]) = pk;
            *(ushort4*)(H16b + (size_t)row * DH + bc) = pk;
        }
    }
    __syncthreads();

    const int nT = DH / BK;   // 16
    for (int t = 0; t < nT; ++t) {
        const int p = t & 1, q = p ^ 1;
        const int k1 = (t + 1) * BK;
        float4 v[4];
        if (t + 1 < nT) {
            // issue next step's loads BEFORE current compute (latency hides under MFMA)
            #pragma unroll
            for (int s = 0; s < 4; ++s) {
                const int rowb = s * 32 + wave * 8;
                const unsigned short* gp = Ab + (size_t)(rowb + ar) * DH + k1 + akb;
                __builtin_amdgcn_global_load_lds(AS1(gp), AS3(&As[q][rowb * BK]), 16, 0, 0);
            }
            #pragma unroll
            for (int s = 0; s < 4; ++s) {
                const int row = br + s * 16;
                v[s] = *(const float4*)(Hb + (size_t)row * DH + k1 + bc);
            }
        }
        // compute current buffer
        #pragma unroll
        for (int ks = 0; ks < 2; ++ks) {
            bf16x8 a[4], bf[2];
            #pragma unroll
            for (int i = 0; i < 4; ++i)
                a[i] = *(const bf16x8*)(&As[p][(wm * 64 + i * 16 + lm) * BK + ks * 32 + quad * 8]);
            #pragma unroll
            for (int j = 0; j < 2; ++j)
                bf[j] = *(const bf16x8*)(&Bs[p][(wn * 32 + j * 16 + lm) * BK + ks * 32 + quad * 8]);
            #pragma unroll
            for (int i = 0; i < 4; ++i)
                #pragma unroll
                for (int j = 0; j < 2; ++j)
                    acc[i][j] = __builtin_amdgcn_mfma_f32_16x16x32_bf16(a[i], bf[j], acc[i][j], 0, 0, 0);
        }
        if (t + 1 < nT) {
            // convert + LDS-write next buffer, spill bf16 H
            #pragma unroll
            for (int s = 0; s < 4; ++s) {
                const int row = br + s * 16;
                ushort4 pk; pk.x = f2bf(v[s].x); pk.y = f2bf(v[s].y);
                pk.z = f2bf(v[s].z); pk.w = f2bf(v[s].w);
                *(ushort4*)(&Bs[q][row * BK + bc]) = pk;
                *(ushort4*)(H16b + (size_t)row * DH + k1 + bc) = pk;
            }
        }
        __syncthreads();
    }

    // epilogue: mask, exp, store bf16 alpha, accumulate row sums
    const int c0 = l0 + wn * 32 + lm;          // column for j=0 (j=1 adds 16)
    const int mk0 = mask[(size_t)b * L_ + c0];
    const int mk1 = mask[(size_t)b * L_ + c0 + 16];
    unsigned short* Arow = alpha + (size_t)b * T_ * L_ + l0 + wn * 32 + lm;
    #pragma unroll
    for (int i = 0; i < 4; ++i) {
        #pragma unroll
        for (int r = 0; r < 4; ++r) {
            const int row = wm * 64 + i * 16 + quad * 4 + r;
            float e0 = mk0 ? 0.f : __expf(acc[i][0][r]);
            float e1 = mk1 ? 0.f : __expf(acc[i][1][r]);
            Arow[(size_t)row * L_]      = f2bf(e0);
            Arow[(size_t)row * L_ + 16] = f2bf(e1);
            float part = e0 + e1;                    // sum over this lane's 2 cols
            part += __shfl_xor(part, 1, 64);
            part += __shfl_xor(part, 2, 64);
            part += __shfl_xor(part, 4, 64);
            part += __shfl_xor(part, 8, 64);         // now = sum over 32 cols (this wn half)
            if (lm == 0) atomicAdd(&rs[row], part);
        }
    }
    __syncthreads();
    if (tid < T_) atomicAdd(&rowsum[(size_t)b * T_ + tid], rs[tid]);
}

// ---------------- Kernel 4: z-partials = alpha_un(bf16) . H16(bf16, swizzled LDS transpose)
// 2-phase double-buffered pipeline. tile 128t x 128d, L-split 8 (K=512 each); grid 512 blocks,
// XCD-swizzled (chunk ch -> XCD ch so alpha chunk is shared in one L2). Clean partial writes.
__global__ __launch_bounds__(256, 2) void z_kernel(const unsigned short* __restrict__ alpha,
                                                   const unsigned short* __restrict__ H16,
                                                   float* __restrict__ part) {
    __shared__ __attribute__((aligned(16))) unsigned short As[2][T_ * BK];   // [t][l]
    __shared__ __attribute__((aligned(16))) unsigned B32[2][128 * 32];       // swizzled [d][lp]
    const int blin = blockIdx.x + 8 * (blockIdx.y + 8 * blockIdx.z);
    const int ch = blin & 7, rest = blin >> 3;
    const int b = rest & 7, d0 = (rest >> 3) * 128;
    const int tid = threadIdx.x, wave = tid >> 6, lane = tid & 63;
    const int Lc = L_ / ZCH;                       // 512
    const unsigned short* Ab = alpha + (size_t)b * T_ * L_ + ch * Lc;
    const unsigned short* Hb = H16 + ((size_t)b * L_ + ch * Lc) * DH + d0;

    const int lm = lane & 15, quad = lane >> 4;
    const int wm = wave >> 1, wn = wave & 1;
    f32x4 acc[4][4] = {};
    const int ar = lane >> 3, akb = (lane & 7) * 8;
    const int dg = tid & 15, lph = tid >> 4;       // dg: d-octet, lph: 4-l-row group
    const int lp0 = 2 * lph;

    // ---- prologue: stage step 0 into buffer 0
    {
        #pragma unroll
        for (int s = 0; s < 4; ++s) {
            const int rowb = s * 32 + wave * 8;
            const unsigned short* gp = Ab + (size_t)(rowb + ar) * L_ + akb;
            __builtin_amdgcn_global_load_lds(AS1(gp), AS3(&As[0][rowb * BK]), 16, 0, 0);
        }
        const unsigned short* r = Hb + (size_t)(4 * lph) * DH + dg * 8;
        u16x8 u[4];
        #pragma unroll
        for (int rr = 0; rr < 4; ++rr)
            u[rr] = *(const u16x8*)(r + (size_t)rr * DH);
        #pragma unroll
        for (int i = 0; i < 8; ++i) {
            const int d   = dg * 8 + i;
            const int rot = ((i + (dg & 7)) << 2) & 31;
            B32[0][d * 32 + ((lp0 + rot) & 31)]     = (unsigned)u[0][i] | ((unsigned)u[1][i] << 16);
            B32[0][d * 32 + ((lp0 + 1 + rot) & 31)] = (unsigned)u[2][i] | ((unsigned)u[3][i] << 16);
        }
    }
    __syncthreads();

    const int nT = Lc / BK;   // 8
    for (int t = 0; t < nT; ++t) {
        const int p = t & 1, q = p ^ 1;
        const int k1 = (t + 1) * BK;
        u16x8 u[4];
        if (t + 1 < nT) {
            #pragma unroll
            for (int s = 0; s < 4; ++s) {
                const int rowb = s * 32 + wave * 8;
                const unsigned short* gp = Ab + (size_t)(rowb + ar) * L_ + k1 + akb;
                __builtin_amdgcn_global_load_lds(AS1(gp), AS3(&As[q][rowb * BK]), 16, 0, 0);
            }
            const unsigned short* r = Hb + (size_t)(k1 + 4 * lph) * DH + dg * 8;
            #pragma unroll
            for (int rr = 0; rr < 4; ++rr)
                u[rr] = *(const u16x8*)(r + (size_t)rr * DH);
        }
        #pragma unroll
        for (int ks = 0; ks < 2; ++ks) {
            bf16x8 a[4], bf[4];
            #pragma unroll
            for (int i = 0; i < 4; ++i)
                a[i] = *(const bf16x8*)(&As[p][(wm * 64 + i * 16 + lm) * BK + ks * 32 + quad * 8]);
            #pragma unroll
            for (int j = 0; j < 4; ++j) {
                const int d   = wn * 64 + j * 16 + lm;
                const int rot = (((d & 7) + ((d >> 3) & 7)) << 2) & 31;
                bf[j] = *(const bf16x8*)(&B32[p][d * 32 + ((ks * 16 + quad * 4 + rot) & 31)]);
            }
            #pragma unroll
            for (int i = 0; i < 4; ++i)
                #pragma unroll
                for (int j = 0; j < 4; ++j)
                    acc[i][j] = __builtin_amdgcn_mfma_f32_16x16x32_bf16(a[i], bf[j], acc[i][j], 0, 0, 0);
        }
        if (t + 1 < nT) {
            #pragma unroll
            for (int i = 0; i < 8; ++i) {
                const int d   = dg * 8 + i;
                const int rot = ((i + (dg & 7)) << 2) & 31;
                B32[q][d * 32 + ((lp0 + rot) & 31)]     = (unsigned)u[0][i] | ((unsigned)u[1][i] << 16);
                B32[q][d * 32 + ((lp0 + 1 + rot) & 31)] = (unsigned)u[2][i] | ((unsigned)u[3][i] << 16);
            }
        }
        __syncthreads();
    }
    float* Cb = part + (((size_t)ch * B_ + b) * T_) * DH + d0;
    #pragma unroll
    for (int i = 0; i < 4; ++i)
        #pragma unroll
        for (int j = 0; j < 4; ++j)
            #pragma unroll
            for (int r = 0; r < 4; ++r)
                Cb[(size_t)(wm * 64 + i * 16 + quad * 4 + r) * DH + wn * 64 + j * 16 + lm] = acc[i][j][r];
}

// ---------------- Kernel 5: Z = (sum of ZCH partial chunks) / rowsum
__global__ __launch_bounds__(256) void zreduce_kernel(const float* __restrict__ p,
                                                      const float* __restrict__ rowsum,
                                                      float* __restrict__ Z) {
    const size_t n = (size_t)B_ * T_ * DH;
    const size_t i = ((size_t)blockIdx.x * 256 + threadIdx.x) * 4;
    const int row = (int)(i >> 10);                // i / DH
    const float inv = 1.0f / rowsum[row];
    float4 o = {0.f, 0.f, 0.f, 0.f};
    #pragma unroll
    for (int c = 0; c < ZCH; ++c) {
        const float4 a = *(const float4*)(p + (size_t)c * n + i);
        o.x += a.x; o.y += a.y; o.z += a.z; o.w += a.w;
    }
    o.x *= inv; o.y *= inv; o.z *= inv; o.w *= inv;
    *(float4*)(Z + i) = o;
}

extern "C" void kernel_launch(void* const* d_in, const int* in_sizes, int n_in,
                              void* d_out, int out_size, void* d_ws, size_t ws_size,
                              hipStream_t stream) {
    const float* H    = (const float*)d_in[0];
    const float* G    = (const float*)d_in[1];
    const int*   mask = (const int*)d_in[2];
    const float* Wk   = (const float*)d_in[3];
    const float* Wq   = (const float*)d_in[4];
    float* Z = (float*)d_out;

    char* ws = (char*)d_ws;
    unsigned short* Wct    = (unsigned short*)ws;                        // 512 KB
    unsigned short* Qk     = (unsigned short*)(ws + ((size_t)1 << 20));  //   2 MB
    unsigned short* alpha  = (unsigned short*)(ws + ((size_t)4 << 20));  //   8 MB
    float*          rowsum = (float*)(ws + ((size_t)13 << 20));          //   4 KB
    unsigned short* H16    = (unsigned short*)(ws + ((size_t)14 << 20)); //  64 MB
    float*          zpart  = (float*)(ws + ((size_t)80 << 20));          // 33.6 MB

    hipMemsetAsync(rowsum, 0, (size_t)B_ * T_ * sizeof(float), stream);
    wct_kernel<<<dim3(DG / 64, DH / 128), 256, 0, stream>>>(Wk, Wq, Wct);
    qproj_kernel<<<dim3(DH / 64, (B_ * T_) / 128), 256, 0, stream>>>(G, Wct, Qk);
    fusedsm_kernel<<<dim3(L_ / 64, B_), 256, 0, stream>>>(Qk, H, mask, alpha, rowsum, H16);
    z_kernel<<<dim3(DH / 128, B_, ZCH), 256, 0, stream>>>(alpha, H16, zpart);
    zreduce_kernel<<<(B_ * T_ * DH / 4) / 256, 256, 0, stream>>>(zpart, rowsum, Z);
}

// Round 3
// 282.867 us; speedup vs baseline: 1.0834x; 1.0120x over previous
//
#include <hip/hip_runtime.h>
#include <hip/hip_bf16.h>
#include <math.h>

#define B_  8
#define L_  4096
#define T_  128
#define DH  1024
#define DG  256
#define DP  256
#define BK  64
#define ZCH 8          // z split-K chunks

typedef short bf16x8 __attribute__((ext_vector_type(8)));
typedef float f32x4  __attribute__((ext_vector_type(4)));
typedef unsigned short u16x8 __attribute__((ext_vector_type(8)));

#define AS1(p) ((const __attribute__((address_space(1))) void*)(p))
#define AS3(p) ((__attribute__((address_space(3))) void*)(p))

// raw barrier: per-wave LDS drain only -- NO vmcnt drain, so global loads stay in flight
#define SYNC() do { asm volatile("s_waitcnt lgkmcnt(0)" ::: "memory"); \
                    __builtin_amdgcn_s_barrier(); \
                    __builtin_amdgcn_sched_barrier(0); } while (0)

__device__ __forceinline__ unsigned short f2bf(float f) {
    unsigned u = __float_as_uint(f);
    unsigned r = (u + 0x7FFFu + ((u >> 16) & 1u)) >> 16;  // RNE
    return (unsigned short)r;
}

// XOR swizzle for [row][64 bf16] LDS tiles (128B row stride): spreads the 16-rows-same-column
// ds_read_b128 pattern across 8 16B slots (16-way conflict -> 2-way, free).
__device__ __forceinline__ char* swz(void* base, int row, int colbytes) {
    return (char*)base + (((row << 7) + colbytes) ^ ((row & 7) << 4));
}
__device__ __forceinline__ const char* swzc(const void* base, int row, int colbytes) {
    return (const char*)base + (((row << 7) + colbytes) ^ ((row & 7) << 4));
}

// ---------------- Kernel W: Wct[d,g] = (1/16) * sum_p Wk[d,p] * Wq[g,p]   (bf16 out)
__global__ __launch_bounds__(256) void wct_kernel(const float* __restrict__ Wk,
                                                  const float* __restrict__ Wq,
                                                  unsigned short* __restrict__ Wct) {
    __shared__ __attribute__((aligned(16))) unsigned short As[128 * BK];
    __shared__ __attribute__((aligned(16))) unsigned short Bs[64 * BK];
    const int n0 = blockIdx.x * 64, m0 = blockIdx.y * 128;
    const int tid = threadIdx.x, wave = tid >> 6, lane = tid & 63;
    const int lm = lane & 15, quad = lane >> 4;
    const int wm = wave >> 1, wn = wave & 1;
    const int bc = (tid & 15) * 4, br = tid >> 4;
    f32x4 acc[4][2] = {};

    for (int k0 = 0; k0 < DP; k0 += BK) {
        #pragma unroll
        for (int s = 0; s < 8; ++s) {
            const int row = br + s * 16;
            const float4 v = *(const float4*)(Wk + (size_t)(m0 + row) * DP + k0 + bc);
            ushort4 p; p.x = f2bf(v.x); p.y = f2bf(v.y); p.z = f2bf(v.z); p.w = f2bf(v.w);
            *(ushort4*)(&As[row * BK + bc]) = p;
        }
        #pragma unroll
        for (int s = 0; s < 4; ++s) {
            const int row = br + s * 16;
            const float4 v = *(const float4*)(Wq + (size_t)(n0 + row) * DP + k0 + bc);
            ushort4 p; p.x = f2bf(v.x); p.y = f2bf(v.y); p.z = f2bf(v.z); p.w = f2bf(v.w);
            *(ushort4*)(&Bs[row * BK + bc]) = p;
        }
        __syncthreads();
        #pragma unroll
        for (int ks = 0; ks < 2; ++ks) {
            bf16x8 a[4], bf[2];
            #pragma unroll
            for (int i = 0; i < 4; ++i)
                a[i] = *(const bf16x8*)(&As[(wm * 64 + i * 16 + lm) * BK + ks * 32 + quad * 8]);
            #pragma unroll
            for (int j = 0; j < 2; ++j)
                bf[j] = *(const bf16x8*)(&Bs[(wn * 32 + j * 16 + lm) * BK + ks * 32 + quad * 8]);
            #pragma unroll
            for (int i = 0; i < 4; ++i)
                #pragma unroll
                for (int j = 0; j < 2; ++j)
                    acc[i][j] = __builtin_amdgcn_mfma_f32_16x16x32_bf16(a[i], bf[j], acc[i][j], 0, 0, 0);
        }
        __syncthreads();
    }
    unsigned short* Cb = Wct + (size_t)m0 * DG + n0;
    #pragma unroll
    for (int i = 0; i < 4; ++i)
        #pragma unroll
        for (int j = 0; j < 2; ++j)
            #pragma unroll
            for (int r = 0; r < 4; ++r)
                Cb[(size_t)(wm * 64 + i * 16 + quad * 4 + r) * DG + wn * 32 + j * 16 + lm] =
                    f2bf(acc[i][j][r] * 0.0625f);
}

// ---------------- Kernel Q: Qk[bt,d] = sum_g G[bt,g] * Wct[d,g]   (bf16 out)
__global__ __launch_bounds__(256) void qproj_kernel(const float* __restrict__ G,
                                                    const unsigned short* __restrict__ Wct,
                                                    unsigned short* __restrict__ Qk) {
    __shared__ __attribute__((aligned(16))) unsigned short As[128 * BK];
    __shared__ __attribute__((aligned(16))) unsigned short Bs[64 * BK];
    const int n0 = blockIdx.x * 64, m0 = blockIdx.y * 128;
    const int tid = threadIdx.x, wave = tid >> 6, lane = tid & 63;
    const int lm = lane & 15, quad = lane >> 4;
    const int wm = wave >> 1, wn = wave & 1;
    const int bc = (tid & 15) * 4, br = tid >> 4;
    const int ar = lane >> 3, akb = (lane & 7) * 8;
    f32x4 acc[4][2] = {};

    for (int k0 = 0; k0 < DG; k0 += BK) {
        #pragma unroll
        for (int s = 0; s < 8; ++s) {
            const int row = br + s * 16;
            const float4 v = *(const float4*)(G + (size_t)(m0 + row) * DG + k0 + bc);
            ushort4 p; p.x = f2bf(v.x); p.y = f2bf(v.y); p.z = f2bf(v.z); p.w = f2bf(v.w);
            *(ushort4*)(&As[row * BK + bc]) = p;
        }
        #pragma unroll
        for (int s = 0; s < 2; ++s) {
            const int rowb = s * 32 + wave * 8;
            const unsigned short* gp = Wct + (size_t)(n0 + rowb + ar) * DG + k0 + akb;
            __builtin_amdgcn_global_load_lds(AS1(gp), AS3(&Bs[rowb * BK]), 16, 0, 0);
        }
        __syncthreads();
        #pragma unroll
        for (int ks = 0; ks < 2; ++ks) {
            bf16x8 a[4], bf[2];
            #pragma unroll
            for (int i = 0; i < 4; ++i)
                a[i] = *(const bf16x8*)(&As[(wm * 64 + i * 16 + lm) * BK + ks * 32 + quad * 8]);
            #pragma unroll
            for (int j = 0; j < 2; ++j)
                bf[j] = *(const bf16x8*)(&Bs[(wn * 32 + j * 16 + lm) * BK + ks * 32 + quad * 8]);
            #pragma unroll
            for (int i = 0; i < 4; ++i)
                #pragma unroll
                for (int j = 0; j < 2; ++j)
                    acc[i][j] = __builtin_amdgcn_mfma_f32_16x16x32_bf16(a[i], bf[j], acc[i][j], 0, 0, 0);
        }
        __syncthreads();
    }
    unsigned short* Cb = Qk + (size_t)m0 * DH + n0;
    #pragma unroll
    for (int i = 0; i < 4; ++i)
        #pragma unroll
        for (int j = 0; j < 2; ++j)
            #pragma unroll
            for (int r = 0; r < 4; ++r)
                Cb[(size_t)(wm * 64 + i * 16 + quad * 4 + r) * DH + wn * 32 + j * 16 + lm] =
                    f2bf(acc[i][j][r]);
}

// ---------------- Kernel S: fused logits+exp. Reg-staged, depth-2 pipeline, raw barriers
// (no vmcnt drain), XOR-swizzled LDS. Writes bf16 H copy (H16); accumulates rowsum.
// tile 128t x 64l, K=1024 in 16 steps; grid 512 blocks, XCD-swizzled (batch b -> XCD b).
__global__ __launch_bounds__(256, 2) void fusedsm_kernel(const unsigned short* __restrict__ Qk,
                                                         const float* __restrict__ H,
                                                         const int* __restrict__ mask,
                                                         unsigned short* __restrict__ alpha,
                                                         float* __restrict__ rowsum,
                                                         unsigned short* __restrict__ H16) {
    __shared__ __attribute__((aligned(16))) unsigned short As[2][T_ * BK];   // [t][k] swizzled
    __shared__ __attribute__((aligned(16))) unsigned short Bs[2][64 * BK];   // [l][k] swizzled
    __shared__ float rs[T_];
    const int blin = blockIdx.x + (L_ / 64) * blockIdx.y;
    const int b = blin & 7, l0 = (blin >> 3) * 64;
    const int tid = threadIdx.x, wave = tid >> 6, lane = tid & 63;
    const unsigned short* Ab = Qk + (size_t)b * T_ * DH;
    const float*          Hb = H + ((size_t)b * L_ + l0) * DH;
    unsigned short*     H16b = H16 + ((size_t)b * L_ + l0) * DH;

    const int lm = lane & 15, quad = lane >> 4;
    const int wm = wave >> 1, wn = wave & 1;
    f32x4 acc[4][2] = {};
    const int ar = lane >> 3, akb = (lane & 7) * 8;     // A-stage: 8B-bf16 granule mapping
    const int bc = (tid & 15) * 4, br = tid >> 4;       // B-stage: 4-float granule mapping

    if (tid < T_) rs[tid] = 0.f;

    u16x8  qa0[4], qa1[4];
    float4 hv0[4], hv1[4];

    auto LOAD = [&](u16x8* qa, float4* hv, int kd) {
        #pragma unroll
        for (int s = 0; s < 4; ++s)
            qa[s] = *(const u16x8*)(Ab + (size_t)(s * 32 + wave * 8 + ar) * DH + kd + akb);
        #pragma unroll
        for (int s = 0; s < 4; ++s)
            hv[s] = *(const float4*)(Hb + (size_t)(br + s * 16) * DH + kd + bc);
    };
    auto WRITE = [&](int buf, const u16x8* qa, const float4* hv, int kd) {
        #pragma unroll
        for (int s = 0; s < 4; ++s)
            *(u16x8*)swz(&As[buf][0], s * 32 + wave * 8 + ar, akb * 2) = qa[s];
        #pragma unroll
        for (int s = 0; s < 4; ++s) {
            const int row = br + s * 16;
            ushort4 pk; pk.x = f2bf(hv[s].x); pk.y = f2bf(hv[s].y);
            pk.z = f2bf(hv[s].z); pk.w = f2bf(hv[s].w);
            *(ushort4*)swz(&Bs[buf][0], row, bc * 2) = pk;
            *(ushort4*)(H16b + (size_t)row * DH + kd + bc) = pk;   // bf16 H for z pass
        }
    };
    auto COMPUTE = [&](int buf) {
        #pragma unroll
        for (int ks = 0; ks < 2; ++ks) {
            bf16x8 a[4], bfv[2];
            #pragma unroll
            for (int i = 0; i < 4; ++i) {
                const int row = wm * 64 + i * 16 + lm;
                a[i] = *(const bf16x8*)swzc(&As[buf][0], row, ks * 64 + quad * 16);
            }
            #pragma unroll
            for (int j = 0; j < 2; ++j) {
                const int row = wn * 32 + j * 16 + lm;
                bfv[j] = *(const bf16x8*)swzc(&Bs[buf][0], row, ks * 64 + quad * 16);
            }
            #pragma unroll
            for (int i = 0; i < 4; ++i)
                #pragma unroll
                for (int j = 0; j < 2; ++j)
                    acc[i][j] = __builtin_amdgcn_mfma_f32_16x16x32_bf16(a[i], bfv[j], acc[i][j], 0, 0, 0);
        }
    };

    const int nT = DH / BK;   // 16 (even)
    // prologue: load d0,d1; stage d0 into LDS[0]
    LOAD(qa0, hv0, 0);
    LOAD(qa1, hv1, BK);
    WRITE(0, qa0, hv0, 0);
    SYNC();

    for (int tt = 0; tt < nT; tt += 2) {
        // even iter (data tt in LDS[0]); set0 free
        if (tt + 2 < nT) LOAD(qa0, hv0, (tt + 2) * BK);
        COMPUTE(0);
        WRITE(1, qa1, hv1, (tt + 1) * BK);
        SYNC();
        // odd iter (data tt+1 in LDS[1]); set1 free
        if (tt + 3 < nT) LOAD(qa1, hv1, (tt + 3) * BK);
        COMPUTE(1);
        if (tt + 2 < nT) WRITE(0, qa0, hv0, (tt + 2) * BK);
        SYNC();
    }

    // epilogue: mask, exp, store bf16 alpha, accumulate row sums
    const int c0 = l0 + wn * 32 + lm;          // column for j=0 (j=1 adds 16)
    const int mk0 = mask[(size_t)b * L_ + c0];
    const int mk1 = mask[(size_t)b * L_ + c0 + 16];
    unsigned short* Arow = alpha + (size_t)b * T_ * L_ + l0 + wn * 32 + lm;
    #pragma unroll
    for (int i = 0; i < 4; ++i) {
        #pragma unroll
        for (int r = 0; r < 4; ++r) {
            const int row = wm * 64 + i * 16 + quad * 4 + r;
            float e0 = mk0 ? 0.f : __expf(acc[i][0][r]);
            float e1 = mk1 ? 0.f : __expf(acc[i][1][r]);
            Arow[(size_t)row * L_]      = f2bf(e0);
            Arow[(size_t)row * L_ + 16] = f2bf(e1);
            float part = e0 + e1;                    // sum over this lane's 2 cols
            part += __shfl_xor(part, 1, 64);
            part += __shfl_xor(part, 2, 64);
            part += __shfl_xor(part, 4, 64);
            part += __shfl_xor(part, 8, 64);         // now = sum over 32 cols (this wn half)
            if (lm == 0) atomicAdd(&rs[row], part);
        }
    }
    __syncthreads();
    if (tid < T_) atomicAdd(&rowsum[(size_t)b * T_ + tid], rs[tid]);
}

// ---------------- Kernel 4: z-partials = alpha_un(bf16) . H16(bf16, rot-swizzled LDS transpose)
// Reg-staged, depth-2 pipeline, raw barriers. tile 128t x 128d, L-split 8 (K=512 each);
// grid 512 blocks, XCD-swizzled (chunk ch -> XCD ch: alpha chunk shared in one L2).
__global__ __launch_bounds__(256, 2) void z_kernel(const unsigned short* __restrict__ alpha,
                                                   const unsigned short* __restrict__ H16,
                                                   float* __restrict__ part) {
    __shared__ __attribute__((aligned(16))) unsigned short As[2][T_ * BK];   // [t][l] swizzled
    __shared__ __attribute__((aligned(16))) unsigned B32[2][128 * 32];       // rot-swizzled [d][lp]
    const int blin = blockIdx.x + 8 * (blockIdx.y + 8 * blockIdx.z);
    const int ch = blin & 7, rest = blin >> 3;
    const int b = rest & 7, d0 = (rest >> 3) * 128;
    const int tid = threadIdx.x, wave = tid >> 6, lane = tid & 63;
    const int Lc = L_ / ZCH;                       // 512
    const unsigned short* Ab = alpha + (size_t)b * T_ * L_ + ch * Lc;
    const unsigned short* Hb = H16 + ((size_t)b * L_ + ch * Lc) * DH + d0;

    const int lm = lane & 15, quad = lane >> 4;
    const int wm = wave >> 1, wn = wave & 1;
    f32x4 acc[4][4] = {};
    const int ar = lane >> 3, akb = (lane & 7) * 8;
    const int dg = tid & 15, lph = tid >> 4;       // dg: d-octet, lph: 4-l-row group
    const int lp0 = 2 * lph;

    u16x8 qa0[4], qa1[4];     // alpha A-tile
    u16x8 hu0[4], hu1[4];     // H16 B-tile (4 l-rows x 8 d)

    auto LOAD = [&](u16x8* qa, u16x8* hu, int kd) {
        #pragma unroll
        for (int s = 0; s < 4; ++s)
            qa[s] = *(const u16x8*)(Ab + (size_t)(s * 32 + wave * 8 + ar) * L_ + kd + akb);
        const unsigned short* r = Hb + (size_t)(kd + 4 * lph) * DH + dg * 8;
        #pragma unroll
        for (int rr = 0; rr < 4; ++rr)
            hu[rr] = *(const u16x8*)(r + (size_t)rr * DH);
    };
    auto WRITE = [&](int buf, const u16x8* qa, const u16x8* hu) {
        #pragma unroll
        for (int s = 0; s < 4; ++s)
            *(u16x8*)swz(&As[buf][0], s * 32 + wave * 8 + ar, akb * 2) = qa[s];
        #pragma unroll
        for (int i = 0; i < 8; ++i) {
            const int d   = dg * 8 + i;
            const int rot = ((i + (dg & 7)) << 2) & 31;
            B32[buf][d * 32 + ((lp0 + rot) & 31)]     = (unsigned)hu[0][i] | ((unsigned)hu[1][i] << 16);
            B32[buf][d * 32 + ((lp0 + 1 + rot) & 31)] = (unsigned)hu[2][i] | ((unsigned)hu[3][i] << 16);
        }
    };
    auto COMPUTE = [&](int buf) {
        #pragma unroll
        for (int ks = 0; ks < 2; ++ks) {
            bf16x8 a[4], bfv[4];
            #pragma unroll
            for (int i = 0; i < 4; ++i) {
                const int row = wm * 64 + i * 16 + lm;
                a[i] = *(const bf16x8*)swzc(&As[buf][0], row, ks * 64 + quad * 16);
            }
            #pragma unroll
            for (int j = 0; j < 4; ++j) {
                const int d   = wn * 64 + j * 16 + lm;
                const int rot = (((d & 7) + ((d >> 3) & 7)) << 2) & 31;
                bfv[j] = *(const bf16x8*)(&B32[buf][d * 32 + ((ks * 16 + quad * 4 + rot) & 31)]);
            }
            #pragma unroll
            for (int i = 0; i < 4; ++i)
                #pragma unroll
                for (int j = 0; j < 4; ++j)
                    acc[i][j] = __builtin_amdgcn_mfma_f32_16x16x32_bf16(a[i], bfv[j], acc[i][j], 0, 0, 0);
        }
    };

    const int nT = Lc / BK;   // 8 (even)
    LOAD(qa0, hu0, 0);
    LOAD(qa1, hu1, BK);
    WRITE(0, qa0, hu0);
    SYNC();

    for (int tt = 0; tt < nT; tt += 2) {
        if (tt + 2 < nT) LOAD(qa0, hu0, (tt + 2) * BK);
        COMPUTE(0);
        WRITE(1, qa1, hu1);
        SYNC();
        if (tt + 3 < nT) LOAD(qa1, hu1, (tt + 3) * BK);
        COMPUTE(1);
        if (tt + 2 < nT) WRITE(0, qa0, hu0);
        SYNC();
    }

    float* Cb = part + (((size_t)ch * B_ + b) * T_) * DH + d0;
    #pragma unroll
    for (int i = 0; i < 4; ++i)
        #pragma unroll
        for (int j = 0; j < 4; ++j)
            #pragma unroll
            for (int r = 0; r < 4; ++r)
                Cb[(size_t)(wm * 64 + i * 16 + quad * 4 + r) * DH + wn * 64 + j * 16 + lm] = acc[i][j][r];
}

// ---------------- Kernel 5: Z = (sum of ZCH partial chunks) / rowsum
__global__ __launch_bounds__(256) void zreduce_kernel(const float* __restrict__ p,
                                                      const float* __restrict__ rowsum,
                                                      float* __restrict__ Z) {
    const size_t n = (size_t)B_ * T_ * DH;
    const size_t i = ((size_t)blockIdx.x * 256 + threadIdx.x) * 4;
    const int row = (int)(i >> 10);                // i / DH
    const float inv = 1.0f / rowsum[row];
    float4 o = {0.f, 0.f, 0.f, 0.f};
    #pragma unroll
    for (int c = 0; c < ZCH; ++c) {
        const float4 a = *(const float4*)(p + (size_t)c * n + i);
        o.x += a.x; o.y += a.y; o.z += a.z; o.w += a.w;
    }
    o.x *= inv; o.y *= inv; o.z *= inv; o.w *= inv;
    *(float4*)(Z + i) = o;
}

extern "C" void kernel_launch(void* const* d_in, const int* in_sizes, int n_in,
                              void* d_out, int out_size, void* d_ws, size_t ws_size,
                              hipStream_t stream) {
    const float* H    = (const float*)d_in[0];
    const float* G    = (const float*)d_in[1];
    const int*   mask = (const int*)d_in[2];
    const float* Wk   = (const float*)d_in[3];
    const float* Wq   = (const float*)d_in[4];
    float* Z = (float*)d_out;

    char* ws = (char*)d_ws;
    unsigned short* Wct    = (unsigned short*)ws;                        // 512 KB
    unsigned short* Qk     = (unsigned short*)(ws + ((size_t)1 << 20));  //   2 MB
    unsigned short* alpha  = (unsigned short*)(ws + ((size_t)4 << 20));  //   8 MB
    float*          rowsum = (float*)(ws + ((size_t)13 << 20));          //   4 KB
    unsigned short* H16    = (unsigned short*)(ws + ((size_t)14 << 20)); //  64 MB
    float*          zpart  = (float*)(ws + ((size_t)80 << 20));          // 33.6 MB

    hipMemsetAsync(rowsum, 0, (size_t)B_ * T_ * sizeof(float), stream);
    wct_kernel<<<dim3(DG / 64, DH / 128), 256, 0, stream>>>(Wk, Wq, Wct);
    qproj_kernel<<<dim3(DH / 64, (B_ * T_) / 128), 256, 0, stream>>>(G, Wct, Qk);
    fusedsm_kernel<<<dim3(L_ / 64, B_), 256, 0, stream>>>(Qk, H, mask, alpha, rowsum, H16);
    z_kernel<<<dim3(DH / 128, B_, ZCH), 256, 0, stream>>>(alpha, H16, zpart);
    zreduce_kernel<<<(B_ * T_ * DH / 4) / 256, 256, 0, stream>>>(zpart, rowsum, Z);
}